// Round 1
// baseline (333.422 us; speedup 1.0000x reference)
//
#include <hip/hip_runtime.h>
#include <hip/hip_bf16.h>

#define B_  2
#define S_  2048
#define D_  1024
#define H_  16
#define DH_ 64

typedef __attribute__((ext_vector_type(8))) short bf16x8;
typedef __attribute__((ext_vector_type(4))) float f32x4;

__device__ __forceinline__ float bf2f(short v) {
  unsigned int u = ((unsigned int)(unsigned short)v) << 16;
  float f; __builtin_memcpy(&f, &u, 4); return f;
}
__device__ __forceinline__ short f2bf(float f) {
  unsigned int u; __builtin_memcpy(&u, &f, 4);
  u = (u + 0x7FFFu + ((u >> 16) & 1u)) >> 16;
  return (short)u;
}

#define GLOAD_LDS16(gp, lp) \
  __builtin_amdgcn_global_load_lds((const __attribute__((address_space(1))) void*)(gp), \
                                   (__attribute__((address_space(3))) void*)(lp), 16, 0, 0)

// ---------------- f32 -> bf16 convert (x) ----------------
__global__ __launch_bounds__(256) void k_cvt(const float* __restrict__ in,
                                             short* __restrict__ out, int n4) {
  int i = blockIdx.x * 256 + threadIdx.x;
  if (i >= n4) return;
  float4 v = ((const float4*)in)[i];
  short4 o; o.x = f2bf(v.x); o.y = f2bf(v.y); o.z = f2bf(v.z); o.w = f2bf(v.w);
  *(short4*)(out + (size_t)i * 4) = o;
}

// ---------------- W (f32 [K][N]) -> Wt (bf16 [N][K]) ----------------
__global__ __launch_bounds__(256) void k_transpose(const float* __restrict__ W,
                                                   short* __restrict__ Wt) {
  __shared__ float tile[32][33];
  int tx = threadIdx.x, ty = threadIdx.y;
  int bx = blockIdx.x * 32, by = blockIdx.y * 32;
  #pragma unroll
  for (int i = 0; i < 32; i += 8)
    tile[ty + i][tx] = W[(size_t)(by + ty + i) * D_ + bx + tx];
  __syncthreads();
  #pragma unroll
  for (int i = 0; i < 32; i += 8)
    Wt[(size_t)(bx + ty + i) * D_ + by + tx] = f2bf(tile[tx][ty + i]);
}

// ---------------- RoPE cos/sin table ----------------
__global__ __launch_bounds__(256) void k_rope_table(float* __restrict__ cosT,
                                                    float* __restrict__ sinT) {
  int i = blockIdx.x * 256 + threadIdx.x;  // S_*32 entries
  int s = i >> 5, d = i & 31;
  float invf = exp2f(-(float)d * (13.287712379549449f / 32.0f)); // 10000^(-d/32)
  float ang = (float)s * invf;
  cosT[i] = cosf(ang);
  sinT[i] = sinf(ang);
}

// ---------------- apply RoPE in-place to q and k (bf16) ----------------
__global__ __launch_bounds__(256) void k_rope(short* __restrict__ qb, short* __restrict__ kb,
                                              const float* __restrict__ cosT,
                                              const float* __restrict__ sinT) {
  int i = blockIdx.x * 256 + threadIdx.x;  // B*S*H*32
  short* buf = blockIdx.y ? kb : qb;
  int d = i & 31;
  int h = (i >> 5) & (H_ - 1);
  int s = (i >> 9) & (S_ - 1);
  int b = i >> 20;
  size_t base = ((size_t)(b * S_ + s)) * D_ + h * DH_ + d;
  float x1 = bf2f(buf[base]), x2 = bf2f(buf[base + 32]);
  int ti = s * 32 + d;
  float co = cosT[ti], si = sinT[ti];
  buf[base]      = f2bf(x1 * co - x2 * si);
  buf[base + 32] = f2bf(x1 * si + x2 * co);
}

// ---------------- bf16 GEMM: C[M,N] = A[M,K] * Bt[N,K]^T + bias ----------------
// m97 structure: 128x128 tile, BK=32, 4 waves (2x2), 4x4 16x16x32 frags/wave.
template <bool OUT_BF16>
__global__ __launch_bounds__(256) void k_gemm(const short* __restrict__ A,
                                              const short* __restrict__ Bt,
                                              const float* __restrict__ bias,
                                              void* __restrict__ out,
                                              int M, int N, int K) {
  __shared__ __align__(16) short lA[128 * 32];
  __shared__ __align__(16) short lB[128 * 32];
  const int tid = threadIdx.x;
  const int wid = tid >> 6, lane = tid & 63;
  const int brow = blockIdx.y * 128, bcol = blockIdx.x * 128;
  const int wr = wid >> 1, wc = wid & 1;
  const int g = lane >> 4, c15 = lane & 15;
  const int sr = lane >> 2, scol = (lane & 3) * 8;
  f32x4 acc[4][4] = {};

  for (int kt = 0; kt < K; kt += 32) {
    __syncthreads();  // protect LDS from previous iteration's readers
    #pragma unroll
    for (int ch = 0; ch < 2; ++ch) {
      const short* ga = A + (size_t)(brow + ch * 64 + wid * 16 + sr) * K + kt + scol;
      const short* gb = Bt + (size_t)(bcol + ch * 64 + wid * 16 + sr) * K + kt + scol;
      GLOAD_LDS16(ga, &lA[(ch * 64 + wid * 16) * 32]);
      GLOAD_LDS16(gb, &lB[(ch * 64 + wid * 16) * 32]);
    }
    __syncthreads();  // drains vmcnt before barrier (compiler-inserted)
    bf16x8 af[4], bfr[4];
    #pragma unroll
    for (int mi = 0; mi < 4; ++mi)
      af[mi] = *(const bf16x8*)&lA[(wr * 64 + mi * 16 + c15) * 32 + g * 8];
    #pragma unroll
    for (int ni = 0; ni < 4; ++ni)
      bfr[ni] = *(const bf16x8*)&lB[(wc * 64 + ni * 16 + c15) * 32 + g * 8];
    #pragma unroll
    for (int mi = 0; mi < 4; ++mi)
      #pragma unroll
      for (int ni = 0; ni < 4; ++ni)
        acc[mi][ni] = __builtin_amdgcn_mfma_f32_16x16x32_bf16(af[mi], bfr[ni], acc[mi][ni], 0, 0, 0);
  }

  #pragma unroll
  for (int mi = 0; mi < 4; ++mi) {
    #pragma unroll
    for (int ni = 0; ni < 4; ++ni) {
      int col = bcol + wc * 64 + ni * 16 + c15;
      float bv = bias[col];
      #pragma unroll
      for (int r = 0; r < 4; ++r) {
        int row = brow + wr * 64 + mi * 16 + g * 4 + r;
        float v = acc[mi][ni][r] + bv;
        if (OUT_BF16) ((short*)out)[(size_t)row * N + col] = f2bf(v);
        else          ((float*)out)[(size_t)row * N + col] = v;
      }
    }
  }
}

// ---------------- causal flash attention ----------------
// grid (S/64, B*H), 256 thr = 4 waves; wave w owns q rows [qt*64+w*16, +16).
__global__ __launch_bounds__(256) void k_flash(const short* __restrict__ Qb,
                                               const short* __restrict__ Kb,
                                               const short* __restrict__ Vb,
                                               short* __restrict__ Ctx) {
  __shared__ __align__(16) short Vt[64][72];      // [dh][kv] padded (+8 -> 16B rows stay aligned)
  __shared__ __align__(16) short Pl[4][16][72];   // [wave][q][kv] padded
  const int qt = blockIdx.x;
  const int bh = blockIdx.y;
  const int b = bh >> 4, h = bh & 15;
  const int tid = threadIdx.x, w = tid >> 6, lane = tid & 63;
  const int g = lane >> 4, c = lane & 15;

  // Q fragments, held in regs across the KV loop
  const size_t qrow = (size_t)b * S_ + qt * 64 + w * 16 + c;
  const short* qp = Qb + qrow * D_ + (size_t)h * DH_;
  bf16x8 qf0 = *(const bf16x8*)(qp + g * 8);
  bf16x8 qf1 = *(const bf16x8*)(qp + 32 + g * 8);

  f32x4 o[4] = {};
  float m[4], l[4];
  #pragma unroll
  for (int r = 0; r < 4; ++r) { m[r] = -1e30f; l[r] = 0.0f; }

  const int nt = qt + 1;
  for (int t = 0; t < nt; ++t) {
    const int kv0 = t * 64;
    // ---- scores = Q * K^T (K read directly from global; L2-resident) ----
    f32x4 sc[4] = {};
    const short* kp = Kb + ((size_t)b * S_ + kv0 + c) * D_ + (size_t)h * DH_;
    #pragma unroll
    for (int n = 0; n < 4; ++n) {
      bf16x8 k0 = *(const bf16x8*)(kp + (size_t)n * 16 * D_ + g * 8);
      bf16x8 k1 = *(const bf16x8*)(kp + (size_t)n * 16 * D_ + 32 + g * 8);
      sc[n] = __builtin_amdgcn_mfma_f32_16x16x32_bf16(qf0, k0, sc[n], 0, 0, 0);
      sc[n] = __builtin_amdgcn_mfma_f32_16x16x32_bf16(qf1, k1, sc[n], 0, 0, 0);
    }
    __syncthreads();  // everyone done reading previous Vt/Pl
    // ---- stage V tile transposed: Vt[dh][kv] ----
    {
      const int kv = tid >> 2, dh0 = (tid & 3) * 16;
      const short* vp = Vb + ((size_t)b * S_ + kv0 + kv) * D_ + (size_t)h * DH_ + dh0;
      bf16x8 v0 = *(const bf16x8*)(vp);
      bf16x8 v1 = *(const bf16x8*)(vp + 8);
      #pragma unroll
      for (int j = 0; j < 8; ++j) Vt[dh0 + j][kv] = v0[j];
      #pragma unroll
      for (int j = 0; j < 8; ++j) Vt[dh0 + 8 + j][kv] = v1[j];
    }
    // ---- scale + causal mask (only diagonal tile needs masking) ----
    const bool diag = (t == qt);
    #pragma unroll
    for (int n = 0; n < 4; ++n)
      #pragma unroll
      for (int r = 0; r < 4; ++r) {
        float v = sc[n][r] * 0.125f;
        if (diag) {
          int q  = qt * 64 + w * 16 + g * 4 + r;
          int kv = kv0 + n * 16 + c;
          if (kv > q) v = -1e30f;
        }
        sc[n][r] = v;
      }
    // ---- online softmax ----
    float corr[4], mx[4];
    #pragma unroll
    for (int r = 0; r < 4; ++r) {
      float x = fmaxf(fmaxf(sc[0][r], sc[1][r]), fmaxf(sc[2][r], sc[3][r]));
      x = fmaxf(x, __shfl_xor(x, 1, 64));
      x = fmaxf(x, __shfl_xor(x, 2, 64));
      x = fmaxf(x, __shfl_xor(x, 4, 64));
      x = fmaxf(x, __shfl_xor(x, 8, 64));
      float mn = fmaxf(m[r], x);
      corr[r] = exp2f((m[r] - mn) * 1.44269504f);
      m[r] = mn; mx[r] = mn;
    }
    float rsum[4] = {0.f, 0.f, 0.f, 0.f};
    #pragma unroll
    for (int n = 0; n < 4; ++n)
      #pragma unroll
      for (int r = 0; r < 4; ++r) {
        float p = exp2f((sc[n][r] - mx[r]) * 1.44269504f);
        sc[n][r] = p;
        rsum[r] += p;
      }
    #pragma unroll
    for (int r = 0; r < 4; ++r) {
      float x = rsum[r];
      x += __shfl_xor(x, 1, 64);
      x += __shfl_xor(x, 2, 64);
      x += __shfl_xor(x, 4, 64);
      x += __shfl_xor(x, 8, 64);
      l[r] = l[r] * corr[r] + x;
    }
    #pragma unroll
    for (int n = 0; n < 4; ++n)
      #pragma unroll
      for (int r = 0; r < 4; ++r)
        o[n][r] *= corr[r];
    // ---- P -> LDS (bf16) ----
    #pragma unroll
    for (int n = 0; n < 4; ++n)
      #pragma unroll
      for (int r = 0; r < 4; ++r)
        Pl[w][g * 4 + r][n * 16 + c] = f2bf(sc[n][r]);
    __syncthreads();  // Vt + Pl ready
    // ---- O += P * V ----
    bf16x8 pa0 = *(const bf16x8*)&Pl[w][c][g * 8];
    bf16x8 pa1 = *(const bf16x8*)&Pl[w][c][32 + g * 8];
    #pragma unroll
    for (int n = 0; n < 4; ++n) {
      bf16x8 vb0 = *(const bf16x8*)&Vt[n * 16 + c][g * 8];
      bf16x8 vb1 = *(const bf16x8*)&Vt[n * 16 + c][32 + g * 8];
      o[n] = __builtin_amdgcn_mfma_f32_16x16x32_bf16(pa0, vb0, o[n], 0, 0, 0);
      o[n] = __builtin_amdgcn_mfma_f32_16x16x32_bf16(pa1, vb1, o[n], 0, 0, 0);
    }
  }
  // ---- epilogue: O /= l, write ctx (bf16, [B*S][D] head-interleaved) ----
  #pragma unroll
  for (int r = 0; r < 4; ++r) {
    float inv = 1.0f / l[r];
    int q = qt * 64 + w * 16 + g * 4 + r;
    short* cp = Ctx + ((size_t)b * S_ + q) * D_ + (size_t)h * DH_;
    #pragma unroll
    for (int n = 0; n < 4; ++n)
      cp[n * 16 + c] = f2bf(o[n][r] * inv);
  }
}

extern "C" void kernel_launch(void* const* d_in, const int* in_sizes, int n_in,
                              void* d_out, int out_size, void* d_ws, size_t ws_size,
                              hipStream_t stream) {
  (void)in_sizes; (void)n_in; (void)out_size; (void)ws_size;
  const float* x  = (const float*)d_in[0];
  const float* Wq = (const float*)d_in[1];
  const float* bq = (const float*)d_in[2];
  const float* Wk = (const float*)d_in[3];
  const float* bk = (const float*)d_in[4];
  const float* Wv = (const float*)d_in[5];
  const float* bv = (const float*)d_in[6];
  const float* Wo = (const float*)d_in[7];
  const float* bo = (const float*)d_in[8];
  float* out = (float*)d_out;
  char* ws = (char*)d_ws;

  const size_t MS = (size_t)B_ * S_;  // 4096
  short* xb  = (short*)(ws);                                  // 8 MB
  short* wqT = (short*)(ws + (size_t)8 * 1024 * 1024);        // 2 MB each
  short* wkT = wqT + (size_t)D_ * D_;
  short* wvT = wkT + (size_t)D_ * D_;
  short* woT = wvT + (size_t)D_ * D_;
  short* qb  = (short*)(ws + (size_t)16 * 1024 * 1024);       // 8 MB each
  short* kb  = qb + MS * D_;
  short* vb  = kb + MS * D_;
  short* ctx = vb + MS * D_;
  float* cosT = (float*)(ws + (size_t)48 * 1024 * 1024);      // 256 KB each
  float* sinT = cosT + (size_t)S_ * 32;

  // 1. x -> bf16
  k_cvt<<<dim3((unsigned)(MS * D_ / 4 / 256)), 256, 0, stream>>>(x, xb, (int)(MS * D_ / 4));
  // 2. weights -> bf16 transposed
  dim3 tb(32, 8);
  k_transpose<<<dim3(32, 32), tb, 0, stream>>>(Wq, wqT);
  k_transpose<<<dim3(32, 32), tb, 0, stream>>>(Wk, wkT);
  k_transpose<<<dim3(32, 32), tb, 0, stream>>>(Wv, wvT);
  k_transpose<<<dim3(32, 32), tb, 0, stream>>>(Wo, woT);
  // 3. rope table
  k_rope_table<<<dim3(S_ * 32 / 256), 256, 0, stream>>>(cosT, sinT);
  // 4. QKV projections
  k_gemm<true><<<dim3(8, 32), 256, 0, stream>>>(xb, wqT, bq, qb, 4096, 1024, 1024);
  k_gemm<true><<<dim3(8, 32), 256, 0, stream>>>(xb, wkT, bk, kb, 4096, 1024, 1024);
  k_gemm<true><<<dim3(8, 32), 256, 0, stream>>>(xb, wvT, bv, vb, 4096, 1024, 1024);
  // 5. RoPE on q,k
  k_rope<<<dim3(B_ * S_ * H_ * 32 / 256, 2), 256, 0, stream>>>(qb, kb, cosT, sinT);
  // 6. causal flash attention
  k_flash<<<dim3(S_ / 64, B_ * H_), 256, 0, stream>>>(qb, kb, vb, ctx);
  // 7. output projection (f32 out)
  k_gemm<false><<<dim3(8, 32), 256, 0, stream>>>(ctx, woT, bo, out, 4096, 1024, 1024);
}

// Round 4
// 244.555 us; speedup vs baseline: 1.3634x; 1.3634x over previous
//
#include <hip/hip_runtime.h>
#include <hip/hip_bf16.h>

#define B_  2
#define S_  2048
#define D_  1024
#define H_  16
#define DH_ 64

typedef __attribute__((ext_vector_type(8))) short bf16x8;
typedef __attribute__((ext_vector_type(4))) float f32x4;

__device__ __forceinline__ float bf2f(short v) {
  unsigned int u = ((unsigned int)(unsigned short)v) << 16;
  float f; __builtin_memcpy(&f, &u, 4); return f;
}
__device__ __forceinline__ short f2bf(float f) {
  unsigned int u; __builtin_memcpy(&u, &f, 4);
  u = (u + 0x7FFFu + ((u >> 16) & 1u)) >> 16;
  return (short)u;
}
__device__ __forceinline__ unsigned pack2(float a, float b) {
  return ((unsigned)(unsigned short)f2bf(a)) | (((unsigned)(unsigned short)f2bf(b)) << 16);
}

#define GLOAD_LDS16(gp, lp) \
  __builtin_amdgcn_global_load_lds((const __attribute__((address_space(1))) void*)(gp), \
                                   (__attribute__((address_space(3))) void*)(lp), 16, 0, 0)

#define MFMA16(a, b, c) __builtin_amdgcn_mfma_f32_16x16x32_bf16(a, b, c, 0, 0, 0)

union U8 { unsigned u[4]; bf16x8 v; };

// ---------------- f32 -> bf16 convert (x) ----------------
__global__ __launch_bounds__(256) void k_cvt(const float* __restrict__ in,
                                             short* __restrict__ out, int n4) {
  int i = blockIdx.x * 256 + threadIdx.x;
  if (i >= n4) return;
  float4 v = ((const float4*)in)[i];
  short4 o; o.x = f2bf(v.x); o.y = f2bf(v.y); o.z = f2bf(v.z); o.w = f2bf(v.w);
  *(short4*)(out + (size_t)i * 4) = o;
}

// ---------------- W (f32 [K][N]) -> Wt (bf16 [N][K]) ----------------
__global__ __launch_bounds__(256) void k_transpose(const float* __restrict__ W,
                                                   short* __restrict__ Wt) {
  __shared__ float tile[32][33];
  int tx = threadIdx.x, ty = threadIdx.y;
  int bx = blockIdx.x * 32, by = blockIdx.y * 32;
  #pragma unroll
  for (int i = 0; i < 32; i += 8)
    tile[ty + i][tx] = W[(size_t)(by + ty + i) * D_ + bx + tx];
  __syncthreads();
  #pragma unroll
  for (int i = 0; i < 32; i += 8)
    Wt[(size_t)(bx + ty + i) * D_ + by + tx] = f2bf(tile[tx][ty + i]);
}

// ---------------- RoPE cos/sin table ----------------
__global__ __launch_bounds__(256) void k_rope_table(float* __restrict__ cosT,
                                                    float* __restrict__ sinT) {
  int i = blockIdx.x * 256 + threadIdx.x;  // S_*32 entries
  int s = i >> 5, d = i & 31;
  float invf = exp2f(-(float)d * (13.287712379549449f / 32.0f)); // 10000^(-d/32)
  float ang = (float)s * invf;
  cosT[i] = cosf(ang);
  sinT[i] = sinf(ang);
}

// ---------------- apply RoPE in-place to q and k (bf16) ----------------
__global__ __launch_bounds__(256) void k_rope(short* __restrict__ qb, short* __restrict__ kb,
                                              const float* __restrict__ cosT,
                                              const float* __restrict__ sinT) {
  int i = blockIdx.x * 256 + threadIdx.x;  // B*S*H*32
  short* buf = blockIdx.y ? kb : qb;
  int d = i & 31;
  int h = (i >> 5) & (H_ - 1);
  int s = (i >> 9) & (S_ - 1);
  int b = i >> 20;
  size_t base = ((size_t)(b * S_ + s)) * D_ + h * DH_ + d;
  float x1 = bf2f(buf[base]), x2 = bf2f(buf[base + 32]);
  int ti = s * 32 + d;
  float co = cosT[ti], si = sinT[ti];
  buf[base]      = f2bf(x1 * co - x2 * si);
  buf[base + 32] = f2bf(x1 * si + x2 * co);
}

// ---------------- bf16 GEMM: C[M,N] = alpha*(A[M,K] * Bt[N,K]^T + bias) ----------------
template <bool OUT_BF16>
__global__ __launch_bounds__(256) void k_gemm(const short* __restrict__ A,
                                              const short* __restrict__ Bt,
                                              const float* __restrict__ bias,
                                              void* __restrict__ out,
                                              int M, int N, int K, float alpha) {
  __shared__ __align__(16) short lA[128 * 32];
  __shared__ __align__(16) short lB[128 * 32];
  const int tid = threadIdx.x;
  const int wid = tid >> 6, lane = tid & 63;
  const int brow = blockIdx.y * 128, bcol = blockIdx.x * 128;
  const int wr = wid >> 1, wc = wid & 1;
  const int g = lane >> 4, c15 = lane & 15;
  const int sr = lane >> 2, scol = (lane & 3) * 8;
  f32x4 acc[4][4] = {};

  for (int kt = 0; kt < K; kt += 32) {
    __syncthreads();
    #pragma unroll
    for (int ch = 0; ch < 2; ++ch) {
      const short* ga = A + (size_t)(brow + ch * 64 + wid * 16 + sr) * K + kt + scol;
      const short* gb = Bt + (size_t)(bcol + ch * 64 + wid * 16 + sr) * K + kt + scol;
      GLOAD_LDS16(ga, &lA[(ch * 64 + wid * 16) * 32]);
      GLOAD_LDS16(gb, &lB[(ch * 64 + wid * 16) * 32]);
    }
    __syncthreads();
    bf16x8 af[4], bfr[4];
    #pragma unroll
    for (int mi = 0; mi < 4; ++mi)
      af[mi] = *(const bf16x8*)&lA[(wr * 64 + mi * 16 + c15) * 32 + g * 8];
    #pragma unroll
    for (int ni = 0; ni < 4; ++ni)
      bfr[ni] = *(const bf16x8*)&lB[(wc * 64 + ni * 16 + c15) * 32 + g * 8];
    #pragma unroll
    for (int mi = 0; mi < 4; ++mi)
      #pragma unroll
      for (int ni = 0; ni < 4; ++ni)
        acc[mi][ni] = MFMA16(af[mi], bfr[ni], acc[mi][ni]);
  }

  #pragma unroll
  for (int mi = 0; mi < 4; ++mi) {
    #pragma unroll
    for (int ni = 0; ni < 4; ++ni) {
      int col = bcol + wc * 64 + ni * 16 + c15;
      float bv = bias[col];
      #pragma unroll
      for (int r = 0; r < 4; ++r) {
        int row = brow + wr * 64 + mi * 16 + g * 4 + r;
        float v = (acc[mi][ni][r] + bv) * alpha;
        if (OUT_BF16) ((short*)out)[(size_t)row * N + col] = f2bf(v);
        else          ((float*)out)[(size_t)row * N + col] = v;
      }
    }
  }
}

// ---------------- causal flash attention ----------------
// Swapped QK^T on 16x16x32 MFMA (all fragment layouts r1-validated).
// grid: 1024 blocks = 32 q-tiles (64 rows, big-first) x 32 bh; 256 thr = 4 waves.
// Wave w owns q rows [qt*64 + w*16, +16). KV tile 64, V^T double-buffered in LDS,
// one barrier per tile. Softmax fully in-register (row = q = lane&15).
// Q pre-scaled by 1/8 in the projection.
__global__ __launch_bounds__(256) void k_flash(const short* __restrict__ Qb,
                                               const short* __restrict__ Kb,
                                               const short* __restrict__ Vb,
                                               short* __restrict__ Ctx) {
  __shared__ __align__(16) short Vt[2][64][72];  // element V[kv][d] at Vt[d][kv^((d>>4)<<3)]
  const int bid = blockIdx.x;
  const int qt  = (S_ / 64 - 1) - (bid >> 5);    // big q-tiles first
  const int bh  = bid & 31;
  const int b   = bh >> 4, h = bh & 15;
  const int tid = threadIdx.x, w = tid >> 6, lane = tid & 63;
  const int g   = lane >> 4, c15 = lane & 15;
  const int qg0 = qt * 64 + w * 16;
  const int qabs = qg0 + c15;

  // Q fragments (B-operand of swapped QK^T): lane holds Q[q=c15][g*8+j (+32)]
  const short* qp = Qb + ((size_t)(b * S_ + qabs)) * D_ + h * DH_ + g * 8;
  bf16x8 qf0 = *(const bf16x8*)qp;
  bf16x8 qf1 = *(const bf16x8*)(qp + 32);

  // V staging: wave w stages d-slice [w*16, w*16+16) for all 64 kv (lane = kv).
  // 2-way LDS write aliasing only (free).
  const int vkv = lane;
  const int vd0 = w * 16;
  const int vcol = vkv ^ (w << 3);  // XOR-swizzled LDS column
  const short* vrow = Vb + (size_t)b * S_ * D_ + h * DH_ + vd0;

  f32x4 o[4] = {};
  float m = -1e30f, l = 0.0f;
  const int nt = qt + 1;

  // prologue: stage tile 0 into buf 0
  {
    const short* vp = vrow + (size_t)vkv * D_;
    bf16x8 a = *(const bf16x8*)vp;
    bf16x8 c = *(const bf16x8*)(vp + 8);
    #pragma unroll
    for (int j = 0; j < 8; ++j) Vt[0][vd0 + j][vcol] = a[j];
    #pragma unroll
    for (int j = 0; j < 8; ++j) Vt[0][vd0 + 8 + j][vcol] = c[j];
  }
  __syncthreads();

  for (int t = 0; t < nt; ++t) {
    const int kv0 = t * 64;
    // early global loads for tile t+1 (latency hidden under QK^T+softmax, T14)
    bf16x8 nv0, nv1;
    if (t + 1 < nt) {
      const short* vp = vrow + (size_t)(kv0 + 64 + vkv) * D_;
      nv0 = *(const bf16x8*)vp;
      nv1 = *(const bf16x8*)(vp + 8);
    }
    // skip compute for tiles fully masked for this wave (staging+barrier still run)
    if (kv0 <= qg0 + 15) {
      // ---- S^T = K * Q^T : A-frag = K rows straight from global/L2 ----
      const short* kp = Kb + ((size_t)(b * S_ + kv0 + c15)) * D_ + h * DH_ + g * 8;
      f32x4 s[4] = {};
      __builtin_amdgcn_s_setprio(1);
      #pragma unroll
      for (int n = 0; n < 4; ++n) {
        bf16x8 k0 = *(const bf16x8*)(kp + (size_t)n * 16 * D_);
        bf16x8 k1 = *(const bf16x8*)(kp + (size_t)n * 16 * D_ + 32);
        s[n] = MFMA16(k0, qf0, s[n]);
        s[n] = MFMA16(k1, qf1, s[n]);
      }
      __builtin_amdgcn_s_setprio(0);
      // lane (g,c15) holds P^T[kv = kv0 + n*16 + g*4 + r][q = qg0 + c15]
      // ---- causal mask ----
      if (kv0 + 63 > qg0) {
        #pragma unroll
        for (int n = 0; n < 4; ++n)
          #pragma unroll
          for (int r = 0; r < 4; ++r)
            if (kv0 + n * 16 + g * 4 + r > qabs) s[n][r] = -1e30f;
      }
      // ---- online softmax (row q = c15; lane-local 16 + xor16 + xor32) ----
      float pm = -1e30f;
      #pragma unroll
      for (int n = 0; n < 4; ++n)
        #pragma unroll
        for (int r = 0; r < 4; ++r) pm = fmaxf(pm, s[n][r]);
      pm = fmaxf(pm, __shfl_xor(pm, 16));
      pm = fmaxf(pm, __shfl_xor(pm, 32));
      if (!__all(pm <= m + 8.0f)) {   // defer-max THR=8
        float nm = fmaxf(m, pm);
        float corr = exp2f((m - nm) * 1.44269504f);
        m = nm; l *= corr;
        float cf[4];
        #pragma unroll
        for (int r = 0; r < 4; ++r) cf[r] = __shfl(corr, g * 4 + r);
        #pragma unroll
        for (int dblk = 0; dblk < 4; ++dblk)
          #pragma unroll
          for (int r = 0; r < 4; ++r) o[dblk][r] *= cf[r];
      }
      float rs = 0.0f;
      #pragma unroll
      for (int n = 0; n < 4; ++n)
        #pragma unroll
        for (int r = 0; r < 4; ++r) {
          float p = exp2f((s[n][r] - m) * 1.44269504f);
          s[n][r] = p; rs += p;
        }
      rs += __shfl_xor(rs, 16);
      rs += __shfl_xor(rs, 32);
      l += rs;
      // ---- pack P^T pairs to bf16 words: pk[n][p] = (s[n][2p], s[n][2p+1]) ----
      unsigned pk[4][2];
      #pragma unroll
      for (int n = 0; n < 4; ++n) {
        pk[n][0] = pack2(s[n][0], s[n][1]);
        pk[n][1] = pack2(s[n][2], s[n][3]);
      }
      // ---- redistribute to PV A-frags: pa[kh] = P[q=c15][kh*32 + g*8 + j] ----
      // Target (g,c15), word widx needs pk[2kh + (g>>1)][widx&1] from lane
      // (2(g&1) + (widx>>1))*16 + c15. The register index depends on the TARGET's
      // g, so shuffle both candidates and select (fixes the R3 bug).
      U8 pa[2];
      #pragma unroll
      for (int kh = 0; kh < 2; ++kh) {
        #pragma unroll
        for (int widx = 0; widx < 4; ++widx) {
          int src = (2 * (g & 1) + (widx >> 1)) * 16 + c15;
          unsigned lo = __shfl(pk[2 * kh][widx & 1], src);
          unsigned hi = __shfl(pk[2 * kh + 1][widx & 1], src);
          pa[kh].u[widx] = (g & 2) ? hi : lo;
        }
      }
      // ---- O += P * V  (B-frag = b128 from transposed, swizzled Vt) ----
      __builtin_amdgcn_s_setprio(1);
      #pragma unroll
      for (int kh = 0; kh < 2; ++kh)
        #pragma unroll
        for (int dblk = 0; dblk < 4; ++dblk) {
          bf16x8 vbf = *(const bf16x8*)&Vt[t & 1][dblk * 16 + c15][kh * 32 + ((g ^ dblk) * 8)];
          o[dblk] = MFMA16(pa[kh].v, vbf, o[dblk]);
        }
      __builtin_amdgcn_s_setprio(0);
    }
    // ---- write staged tile t+1 into the other buffer ----
    if (t + 1 < nt) {
      #pragma unroll
      for (int j = 0; j < 8; ++j) Vt[(t + 1) & 1][vd0 + j][vcol] = nv0[j];
      #pragma unroll
      for (int j = 0; j < 8; ++j) Vt[(t + 1) & 1][vd0 + 8 + j][vcol] = nv1[j];
    }
    __syncthreads();
  }
  // ---- epilogue: normalize, store ctx ----
  float linv = 1.0f / l;
  float lf[4];
  #pragma unroll
  for (int r = 0; r < 4; ++r) lf[r] = __shfl(linv, g * 4 + r);
  #pragma unroll
  for (int dblk = 0; dblk < 4; ++dblk)
    #pragma unroll
    for (int r = 0; r < 4; ++r) {
      int q = qg0 + g * 4 + r;
      Ctx[((size_t)(b * S_ + q)) * D_ + h * DH_ + dblk * 16 + c15] = f2bf(o[dblk][r] * lf[r]);
    }
}

extern "C" void kernel_launch(void* const* d_in, const int* in_sizes, int n_in,
                              void* d_out, int out_size, void* d_ws, size_t ws_size,
                              hipStream_t stream) {
  (void)in_sizes; (void)n_in; (void)out_size; (void)ws_size;
  const float* x  = (const float*)d_in[0];
  const float* Wq = (const float*)d_in[1];
  const float* bq = (const float*)d_in[2];
  const float* Wk = (const float*)d_in[3];
  const float* bk = (const float*)d_in[4];
  const float* Wv = (const float*)d_in[5];
  const float* bv = (const float*)d_in[6];
  const float* Wo = (const float*)d_in[7];
  const float* bo = (const float*)d_in[8];
  float* out = (float*)d_out;
  char* ws = (char*)d_ws;

  const size_t MS = (size_t)B_ * S_;  // 4096
  short* xb  = (short*)(ws);                                  // 8 MB
  short* wqT = (short*)(ws + (size_t)8 * 1024 * 1024);        // 2 MB each
  short* wkT = wqT + (size_t)D_ * D_;
  short* wvT = wkT + (size_t)D_ * D_;
  short* woT = wvT + (size_t)D_ * D_;
  short* qb  = (short*)(ws + (size_t)16 * 1024 * 1024);       // 8 MB each
  short* kb  = qb + MS * D_;
  short* vb  = kb + MS * D_;
  short* ctx = vb + MS * D_;
  float* cosT = (float*)(ws + (size_t)48 * 1024 * 1024);      // 256 KB each
  float* sinT = cosT + (size_t)S_ * 32;

  // 1. x -> bf16
  k_cvt<<<dim3((unsigned)(MS * D_ / 4 / 256)), 256, 0, stream>>>(x, xb, (int)(MS * D_ / 4));
  // 2. weights -> bf16 transposed
  dim3 tb(32, 8);
  k_transpose<<<dim3(32, 32), tb, 0, stream>>>(Wq, wqT);
  k_transpose<<<dim3(32, 32), tb, 0, stream>>>(Wk, wkT);
  k_transpose<<<dim3(32, 32), tb, 0, stream>>>(Wv, wvT);
  k_transpose<<<dim3(32, 32), tb, 0, stream>>>(Wo, woT);
  // 3. rope table
  k_rope_table<<<dim3(S_ * 32 / 256), 256, 0, stream>>>(cosT, sinT);
  // 4. QKV projections (1/sqrt(DH)=1/8 folded into Q; commutes with RoPE rotation)
  k_gemm<true><<<dim3(8, 32), 256, 0, stream>>>(xb, wqT, bq, qb, 4096, 1024, 1024, 0.125f);
  k_gemm<true><<<dim3(8, 32), 256, 0, stream>>>(xb, wkT, bk, kb, 4096, 1024, 1024, 1.0f);
  k_gemm<true><<<dim3(8, 32), 256, 0, stream>>>(xb, wvT, bv, vb, 4096, 1024, 1024, 1.0f);
  // 5. RoPE on q,k
  k_rope<<<dim3(B_ * S_ * H_ * 32 / 256, 2), 256, 0, stream>>>(qb, kb, cosT, sinT);
  // 6. causal flash attention (swapped QK^T, validated 16x16 fragment layouts)
  k_flash<<<dim3((S_ / 64) * 32), 256, 0, stream>>>(qb, kb, vb, ctx);
  // 7. output projection (f32 out)
  k_gemm<false><<<dim3(8, 32), 256, 0, stream>>>(ctx, woT, bo, out, 4096, 1024, 1024, 1.0f);
}

// Round 5
// 144.646 us; speedup vs baseline: 2.3051x; 1.6907x over previous
//
#include <hip/hip_runtime.h>
#include <hip/hip_bf16.h>

#define B_  2
#define S_  2048
#define D_  1024
#define H_  16
#define DH_ 64

typedef __attribute__((ext_vector_type(8))) short bf16x8;
typedef __attribute__((ext_vector_type(4))) float f32x4;

__device__ __forceinline__ short f2bf(float f) {
  unsigned int u; __builtin_memcpy(&u, &f, 4);
  u = (u + 0x7FFFu + ((u >> 16) & 1u)) >> 16;
  return (short)u;
}
// packed f32x2 -> bf16x2 (RNE), lo = first arg  [T12 recipe, no builtin on gfx950]
__device__ __forceinline__ unsigned cvtpk(float a, float b) {
  unsigned r;
  asm("v_cvt_pk_bf16_f32 %0, %1, %2" : "=v"(r) : "v"(a), "v"(b));
  return r;
}

#define GLOAD_LDS16(gp, lp) \
  __builtin_amdgcn_global_load_lds((const __attribute__((address_space(1))) void*)(gp), \
                                   (__attribute__((address_space(3))) void*)(lp), 16, 0, 0)

#define MFMA16(a, b, c) __builtin_amdgcn_mfma_f32_16x16x32_bf16(a, b, c, 0, 0, 0)

union U8 { unsigned u[4]; bf16x8 v; };

// ---------------- f32 -> bf16 convert (x) ----------------
__global__ __launch_bounds__(256) void k_cvt(const float* __restrict__ in,
                                             short* __restrict__ out, int n4) {
  int i = blockIdx.x * 256 + threadIdx.x;
  if (i >= n4) return;
  float4 v = ((const float4*)in)[i];
  short4 o; o.x = f2bf(v.x); o.y = f2bf(v.y); o.z = f2bf(v.z); o.w = f2bf(v.w);
  *(short4*)(out + (size_t)i * 4) = o;
}

// ---------------- W (f32 [K][N]) -> Wt (bf16 [N][K]) ----------------
__global__ __launch_bounds__(256) void k_transpose(const float* __restrict__ W,
                                                   short* __restrict__ Wt) {
  __shared__ float tile[32][33];
  int tx = threadIdx.x, ty = threadIdx.y;
  int bx = blockIdx.x * 32, by = blockIdx.y * 32;
  #pragma unroll
  for (int i = 0; i < 32; i += 8)
    tile[ty + i][tx] = W[(size_t)(by + ty + i) * D_ + bx + tx];
  __syncthreads();
  #pragma unroll
  for (int i = 0; i < 32; i += 8)
    Wt[(size_t)(bx + ty + i) * D_ + by + tx] = f2bf(tile[tx][ty + i]);
}

// ---------------- RoPE cos/sin table ----------------
__global__ __launch_bounds__(256) void k_rope_table(float* __restrict__ cosT,
                                                    float* __restrict__ sinT) {
  int i = blockIdx.x * 256 + threadIdx.x;  // S_*32 entries
  int s = i >> 5, d = i & 31;
  float invf = exp2f(-(float)d * (13.287712379549449f / 32.0f)); // 10000^(-d/32)
  float ang = (float)s * invf;
  cosT[i] = cosf(ang);
  sinT[i] = sinf(ang);
}

// ---------------- fused QKV GEMM + bias + RoPE epilogue ----------------
// C[4096,3072] = xb[4096,1024] * WqkvT[3072,1024]^T ; per-segment bias/alpha;
// RoPE applied to q,k segments in-register (thread holds both rotation halves).
// Q segment pre-scaled by (1/8)*log2(e) so flash softmax uses exp2 directly.
__global__ __launch_bounds__(256) void k_gemm_qkv(const short* __restrict__ A,
                                                  const short* __restrict__ Bt,
                                                  const float* __restrict__ bq,
                                                  const float* __restrict__ bk,
                                                  const float* __restrict__ bv,
                                                  const float* __restrict__ cosT,
                                                  const float* __restrict__ sinT,
                                                  short* __restrict__ qb,
                                                  short* __restrict__ kb,
                                                  short* __restrict__ vb) {
  const int K = 1024;
  __shared__ __align__(16) short lA[128 * 32];
  __shared__ __align__(16) short lB[128 * 32];
  const int tid = threadIdx.x;
  const int wid = tid >> 6, lane = tid & 63;
  const int brow = blockIdx.y * 128, bcol = blockIdx.x * 128;
  const int wr = wid >> 1, wc = wid & 1;
  const int g = lane >> 4, c15 = lane & 15;
  const int sr = lane >> 2, scol = (lane & 3) * 8;
  f32x4 acc[4][4] = {};

  for (int kt = 0; kt < K; kt += 32) {
    __syncthreads();
    #pragma unroll
    for (int ch = 0; ch < 2; ++ch) {
      const short* ga = A + (size_t)(brow + ch * 64 + wid * 16 + sr) * K + kt + scol;
      const short* gb = Bt + (size_t)(bcol + ch * 64 + wid * 16 + sr) * K + kt + scol;
      GLOAD_LDS16(ga, &lA[(ch * 64 + wid * 16) * 32]);
      GLOAD_LDS16(gb, &lB[(ch * 64 + wid * 16) * 32]);
    }
    __syncthreads();
    bf16x8 af[4], bfr[4];
    #pragma unroll
    for (int mi = 0; mi < 4; ++mi)
      af[mi] = *(const bf16x8*)&lA[(wr * 64 + mi * 16 + c15) * 32 + g * 8];
    #pragma unroll
    for (int ni = 0; ni < 4; ++ni)
      bfr[ni] = *(const bf16x8*)&lB[(wc * 64 + ni * 16 + c15) * 32 + g * 8];
    #pragma unroll
    for (int mi = 0; mi < 4; ++mi)
      #pragma unroll
      for (int ni = 0; ni < 4; ++ni)
        acc[mi][ni] = MFMA16(af[mi], bfr[ni], acc[mi][ni]);
  }

  // epilogue: segment select (block-uniform), bias, alpha, rope pair rotation
  const int seg = bcol >> 10;                       // 0=q 1=k 2=v
  const float* bp = (seg == 0) ? bq : (seg == 1) ? bk : bv;
  short* dst = (seg == 0) ? qb : (seg == 1) ? kb : vb;
  const float alpha = (seg == 0) ? 0.18033688f : 1.0f;  // (1/8)*log2(e)
  const bool rope = (seg < 2);
  #pragma unroll
  for (int mi = 0; mi < 4; ++mi) {
    #pragma unroll
    for (int ni = 0; ni < 2; ++ni) {
      int col  = bcol + wc * 64 + ni * 16 + c15;
      int lcol = col & 1023;
      int d    = col & 63;                          // 0..31 (ni<2)
      float b1 = bp[lcol], b2 = bp[lcol + 32];
      #pragma unroll
      for (int r = 0; r < 4; ++r) {
        int row = brow + wr * 64 + mi * 16 + g * 4 + r;
        float x1 = (acc[mi][ni][r]     + b1) * alpha;
        float x2 = (acc[mi][ni + 2][r] + b2) * alpha;
        float o1 = x1, o2 = x2;
        if (rope) {
          int s = row & (S_ - 1);
          float co = cosT[s * 32 + d], si = sinT[s * 32 + d];
          o1 = x1 * co - x2 * si;
          o2 = x1 * si + x2 * co;
        }
        dst[(size_t)row * 1024 + lcol]      = f2bf(o1);
        dst[(size_t)row * 1024 + lcol + 32] = f2bf(o2);
      }
    }
  }
}

// ---------------- bf16 GEMM (Wo): C[M,N] = A[M,K]*Bt[N,K]^T + bias, f32 out ----------------
__global__ __launch_bounds__(256) void k_gemm(const short* __restrict__ A,
                                              const short* __restrict__ Bt,
                                              const float* __restrict__ bias,
                                              float* __restrict__ out,
                                              int M, int N, int K) {
  __shared__ __align__(16) short lA[128 * 32];
  __shared__ __align__(16) short lB[128 * 32];
  const int tid = threadIdx.x;
  const int wid = tid >> 6, lane = tid & 63;
  const int brow = blockIdx.y * 128, bcol = blockIdx.x * 128;
  const int wr = wid >> 1, wc = wid & 1;
  const int g = lane >> 4, c15 = lane & 15;
  const int sr = lane >> 2, scol = (lane & 3) * 8;
  f32x4 acc[4][4] = {};

  for (int kt = 0; kt < K; kt += 32) {
    __syncthreads();
    #pragma unroll
    for (int ch = 0; ch < 2; ++ch) {
      const short* ga = A + (size_t)(brow + ch * 64 + wid * 16 + sr) * K + kt + scol;
      const short* gb = Bt + (size_t)(bcol + ch * 64 + wid * 16 + sr) * K + kt + scol;
      GLOAD_LDS16(ga, &lA[(ch * 64 + wid * 16) * 32]);
      GLOAD_LDS16(gb, &lB[(ch * 64 + wid * 16) * 32]);
    }
    __syncthreads();
    bf16x8 af[4], bfr[4];
    #pragma unroll
    for (int mi = 0; mi < 4; ++mi)
      af[mi] = *(const bf16x8*)&lA[(wr * 64 + mi * 16 + c15) * 32 + g * 8];
    #pragma unroll
    for (int ni = 0; ni < 4; ++ni)
      bfr[ni] = *(const bf16x8*)&lB[(wc * 64 + ni * 16 + c15) * 32 + g * 8];
    #pragma unroll
    for (int mi = 0; mi < 4; ++mi)
      #pragma unroll
      for (int ni = 0; ni < 4; ++ni)
        acc[mi][ni] = MFMA16(af[mi], bfr[ni], acc[mi][ni]);
  }

  #pragma unroll
  for (int mi = 0; mi < 4; ++mi) {
    #pragma unroll
    for (int ni = 0; ni < 4; ++ni) {
      int col = bcol + wc * 64 + ni * 16 + c15;
      float bv = bias[col];
      #pragma unroll
      for (int r = 0; r < 4; ++r) {
        int row = brow + wr * 64 + mi * 16 + g * 4 + r;
        out[(size_t)row * N + col] = acc[mi][ni][r] + bv;
      }
    }
  }
}

// ---------------- causal flash attention ----------------
// Swapped QK^T on 16x16x32 MFMA. grid: 1024 blocks = 32 q-tiles (big-first) x 32 bh;
// 4 waves, wave w owns q rows [qt*64+w*16, +16). KV tile 64.
// K staged once/block via global_load_lds (swizzled, double-buffered, 1-tile prefetch);
// V reg-staged transposed (validated R4). Softmax in-register, exp2-direct
// (Q pre-scaled by (1/8)*log2e in projection). One barrier per tile.
__global__ __launch_bounds__(256) void k_flash(const short* __restrict__ Qb,
                                               const short* __restrict__ Kb,
                                               const short* __restrict__ Vb,
                                               short* __restrict__ Ctx) {
  __shared__ __align__(16) short Vt[2][64][72];  // V[kv][d] at Vt[d][kv^((d>>4)<<3)]
  __shared__ __align__(16) short Kl[2][4096];    // K[kv][d] at kv*64 + ((d>>3)^(kv&7))*8 + (d&7)
  const int bid = blockIdx.x;
  const int qt  = (S_ / 64 - 1) - (bid >> 5);    // big q-tiles first
  const int bh  = bid & 31;
  const int b   = bh >> 4, h = bh & 15;
  const int tid = threadIdx.x, w = tid >> 6, lane = tid & 63;
  const int g   = lane >> 4, c15 = lane & 15;
  const int qg0 = qt * 64 + w * 16;
  const int qabs = qg0 + c15;

  // Q fragments (B-operand of swapped QK^T): lane holds Q[q=c15][g*8+j (+32)]
  const short* qp = Qb + ((size_t)(b * S_ + qabs)) * D_ + h * DH_ + g * 8;
  bf16x8 qf0 = *(const bf16x8*)qp;
  bf16x8 qf1 = *(const bf16x8*)(qp + 32);

  // V staging: wave w stages d-slice [w*16, +16) for all 64 kv (lane = kv)
  const int vkv = lane;
  const int vd0 = w * 16;
  const int vcol = vkv ^ (w << 3);
  const short* vrow = Vb + (size_t)b * S_ * D_ + h * DH_ + vd0;

  // K staging (DMA): wave w covers idx = w*128 + it*64 + lane, 16B each
  const short* kbase = Kb + (size_t)b * S_ * D_ + h * DH_;
  const int kidx0 = w * 128 + lane;
  const int kkv0 = kidx0 >> 3, kdb0 = (kidx0 & 7) ^ (kkv0 & 7);
  const int kidx1 = kidx0 + 64;
  const int kkv1 = kidx1 >> 3, kdb1 = (kidx1 & 7) ^ (kkv1 & 7);

  f32x4 o[4] = {};
  float m = -1e30f, l = 0.0f;
  const int nt = qt + 1;

  // prologue: stage K tile 0 (DMA) + V tile 0 into buf 0
  GLOAD_LDS16(kbase + (size_t)kkv0 * D_ + kdb0 * 8, &Kl[0][(w * 128) * 8]);
  GLOAD_LDS16(kbase + (size_t)kkv1 * D_ + kdb1 * 8, &Kl[0][(w * 128 + 64) * 8]);
  {
    const short* vp = vrow + (size_t)vkv * D_;
    bf16x8 a = *(const bf16x8*)vp;
    bf16x8 c = *(const bf16x8*)(vp + 8);
    #pragma unroll
    for (int j = 0; j < 8; ++j) Vt[0][vd0 + j][vcol] = a[j];
    #pragma unroll
    for (int j = 0; j < 8; ++j) Vt[0][vd0 + 8 + j][vcol] = c[j];
  }
  __syncthreads();

  for (int t = 0; t < nt; ++t) {
    const int kv0 = t * 64;
    // prefetch tile t+1: K via async DMA into other buffer, V into regs (T14)
    bf16x8 nv0, nv1;
    if (t + 1 < nt) {
      const short* kb2 = kbase + (size_t)(kv0 + 64) * D_;
      GLOAD_LDS16(kb2 + (size_t)kkv0 * D_ + kdb0 * 8, &Kl[(t + 1) & 1][(w * 128) * 8]);
      GLOAD_LDS16(kb2 + (size_t)kkv1 * D_ + kdb1 * 8, &Kl[(t + 1) & 1][(w * 128 + 64) * 8]);
      const short* vp = vrow + (size_t)(kv0 + 64 + vkv) * D_;
      nv0 = *(const bf16x8*)vp;
      nv1 = *(const bf16x8*)(vp + 8);
    }
    // ---- S^T = K * Q^T : A-frag = K rows from LDS (swizzled, ~2-way banks) ----
    const short* ks = &Kl[t & 1][0];
    f32x4 s[4] = {};
    __builtin_amdgcn_s_setprio(1);
    #pragma unroll
    for (int n = 0; n < 4; ++n) {
      int krow = (n * 16 + c15) * 64;
      bf16x8 k0 = *(const bf16x8*)&ks[krow + ((g ^ (c15 & 7)) * 8)];
      bf16x8 k1 = *(const bf16x8*)&ks[krow + (((g + 4) ^ (c15 & 7)) * 8)];
      s[n] = MFMA16(k0, qf0, s[n]);
      s[n] = MFMA16(k1, qf1, s[n]);
    }
    __builtin_amdgcn_s_setprio(0);
    // lane (g,c15) holds P^T[kv = kv0 + n*16 + g*4 + r][q = qg0 + c15] (log2-scaled)
    // ---- causal mask (diagonal tile only; wave-uniform branch) ----
    if (kv0 + 63 > qg0) {
      #pragma unroll
      for (int n = 0; n < 4; ++n)
        #pragma unroll
        for (int r = 0; r < 4; ++r)
          if (kv0 + n * 16 + g * 4 + r > qabs) s[n][r] = -1e30f;
    }
    // ---- online softmax (log2 domain; row q = c15) ----
    float pm = -1e30f;
    #pragma unroll
    for (int n = 0; n < 4; ++n)
      #pragma unroll
      for (int r = 0; r < 4; ++r) pm = fmaxf(pm, s[n][r]);
    pm = fmaxf(pm, __shfl_xor(pm, 16));
    pm = fmaxf(pm, __shfl_xor(pm, 32));
    if (!__all(pm <= m + 8.0f)) {   // defer-max THR=8 (log2 units; P <= 256)
      float nm = fmaxf(m, pm);
      float corr = exp2f(m - nm);
      m = nm; l *= corr;
      float cf[4];
      #pragma unroll
      for (int r = 0; r < 4; ++r) cf[r] = __shfl(corr, g * 4 + r);
      #pragma unroll
      for (int dblk = 0; dblk < 4; ++dblk)
        #pragma unroll
        for (int r = 0; r < 4; ++r) o[dblk][r] *= cf[r];
    }
    float rs = 0.0f;
    #pragma unroll
    for (int n = 0; n < 4; ++n)
      #pragma unroll
      for (int r = 0; r < 4; ++r) {
        float p = exp2f(s[n][r] - m);
        s[n][r] = p; rs += p;
      }
    rs += __shfl_xor(rs, 16);
    rs += __shfl_xor(rs, 32);
    l += rs;
    // ---- pack P^T pairs to bf16 words (v_cvt_pk, 1 instr per pair) ----
    unsigned pk[4][2];
    #pragma unroll
    for (int n = 0; n < 4; ++n) {
      pk[n][0] = cvtpk(s[n][0], s[n][1]);
      pk[n][1] = cvtpk(s[n][2], s[n][3]);
    }
    // ---- redistribute to PV A-frags: pa[kh] = P[q=c15][kh*32 + g*8 + j] ----
    U8 pa[2];
    #pragma unroll
    for (int kh = 0; kh < 2; ++kh) {
      #pragma unroll
      for (int widx = 0; widx < 4; ++widx) {
        int src = (2 * (g & 1) + (widx >> 1)) * 16 + c15;
        unsigned lo = __shfl(pk[2 * kh][widx & 1], src);
        unsigned hi = __shfl(pk[2 * kh + 1][widx & 1], src);
        pa[kh].u[widx] = (g & 2) ? hi : lo;
      }
    }
    // ---- O += P * V  (B-frag = b128 from transposed, swizzled Vt) ----
    __builtin_amdgcn_s_setprio(1);
    #pragma unroll
    for (int kh = 0; kh < 2; ++kh)
      #pragma unroll
      for (int dblk = 0; dblk < 4; ++dblk) {
        bf16x8 vbf = *(const bf16x8*)&Vt[t & 1][dblk * 16 + c15][kh * 32 + ((g ^ dblk) * 8)];
        o[dblk] = MFMA16(pa[kh].v, vbf, o[dblk]);
      }
    __builtin_amdgcn_s_setprio(0);
    // ---- write staged V tile t+1 ----
    if (t + 1 < nt) {
      #pragma unroll
      for (int j = 0; j < 8; ++j) Vt[(t + 1) & 1][vd0 + j][vcol] = nv0[j];
      #pragma unroll
      for (int j = 0; j < 8; ++j) Vt[(t + 1) & 1][vd0 + 8 + j][vcol] = nv1[j];
    }
    __syncthreads();  // drains vmcnt (K DMA) + orders LDS for next tile
  }
  // ---- epilogue: normalize, store ctx ----
  float linv = 1.0f / l;
  float lf[4];
  #pragma unroll
  for (int r = 0; r < 4; ++r) lf[r] = __shfl(linv, g * 4 + r);
  #pragma unroll
  for (int dblk = 0; dblk < 4; ++dblk)
    #pragma unroll
    for (int r = 0; r < 4; ++r) {
      int q = qg0 + g * 4 + r;
      Ctx[((size_t)(b * S_ + q)) * D_ + h * DH_ + dblk * 16 + c15] = f2bf(o[dblk][r] * lf[r]);
    }
}

extern "C" void kernel_launch(void* const* d_in, const int* in_sizes, int n_in,
                              void* d_out, int out_size, void* d_ws, size_t ws_size,
                              hipStream_t stream) {
  (void)in_sizes; (void)n_in; (void)out_size; (void)ws_size;
  const float* x  = (const float*)d_in[0];
  const float* Wq = (const float*)d_in[1];
  const float* bq = (const float*)d_in[2];
  const float* Wk = (const float*)d_in[3];
  const float* bk = (const float*)d_in[4];
  const float* Wv = (const float*)d_in[5];
  const float* bv = (const float*)d_in[6];
  const float* Wo = (const float*)d_in[7];
  const float* bo = (const float*)d_in[8];
  float* out = (float*)d_out;
  char* ws = (char*)d_ws;

  const size_t MS = (size_t)B_ * S_;  // 4096
  short* xb  = (short*)(ws);                                  // 8 MB
  short* wqT = (short*)(ws + (size_t)8 * 1024 * 1024);        // 2 MB each, contiguous
  short* wkT = wqT + (size_t)D_ * D_;
  short* wvT = wkT + (size_t)D_ * D_;
  short* woT = wvT + (size_t)D_ * D_;
  short* qb  = (short*)(ws + (size_t)16 * 1024 * 1024);       // 8 MB each
  short* kb  = qb + MS * D_;
  short* vb  = kb + MS * D_;
  short* ctx = vb + MS * D_;
  float* cosT = (float*)(ws + (size_t)48 * 1024 * 1024);      // 256 KB each
  float* sinT = cosT + (size_t)S_ * 32;

  // 1. x -> bf16
  k_cvt<<<dim3((unsigned)(MS * D_ / 4 / 256)), 256, 0, stream>>>(x, xb, (int)(MS * D_ / 4));
  // 2. weights -> bf16 transposed (wq/wk/wv contiguous => one [3072][1024] matrix)
  dim3 tb(32, 8);
  k_transpose<<<dim3(32, 32), tb, 0, stream>>>(Wq, wqT);
  k_transpose<<<dim3(32, 32), tb, 0, stream>>>(Wk, wkT);
  k_transpose<<<dim3(32, 32), tb, 0, stream>>>(Wv, wvT);
  k_transpose<<<dim3(32, 32), tb, 0, stream>>>(Wo, woT);
  // 3. rope table (needed by QKV epilogue)
  k_rope_table<<<dim3(S_ * 32 / 256), 256, 0, stream>>>(cosT, sinT);
  // 4. fused QKV projection + bias + RoPE (+ (1/8)*log2e fold into Q)
  k_gemm_qkv<<<dim3(24, 32), 256, 0, stream>>>(xb, wqT, bq, bk, bv, cosT, sinT, qb, kb, vb);
  // 5. causal flash attention
  k_flash<<<dim3((S_ / 64) * 32), 256, 0, stream>>>(qb, kb, vb, ctx);
  // 6. output projection (f32 out)
  k_gemm<<<dim3(8, 32), 256, 0, stream>>>(ctx, woT, bo, out, 4096, 1024, 1024);
}